// Round 12
// baseline (243.026 us; speedup 1.0000x reference)
//
#include <hip/hip_runtime.h>
#include <cstdint>
#include <cstddef>
#include <math.h>

typedef _Float16 half8 __attribute__((ext_vector_type(8)));
typedef _Float16 half4 __attribute__((ext_vector_type(4)));
typedef float f32x4 __attribute__((ext_vector_type(4)));
typedef float f32x16 __attribute__((ext_vector_type(16)));
typedef unsigned int uint2v __attribute__((ext_vector_type(2)));

#define NB  2
#define NT  2048
#define NC  1024
#define NH  16
#define ND  64

__device__ __forceinline__ void gload_lds16(const _Float16* g, _Float16* l) {
  __builtin_amdgcn_global_load_lds((const __attribute__((address_space(1))) void*)g,
                                   (__attribute__((address_space(3))) void*)l, 16, 0, 0);
}

// v_permlane32_swap_b32: r[0]={a.lo,b.lo}, r[1]={a.hi,b.hi}.
// NEVER call with a==b (same SSA value) — regalloc coalescing makes it a self-swap.
__device__ __forceinline__ uint2v plswap(unsigned a, unsigned b) {
  return __builtin_amdgcn_permlane32_swap(a, b, false, false);
}

// ---------------- convert x -> fp16 ----------------
__global__ void k_cvt_x(const float* __restrict__ x, _Float16* __restrict__ xh) {
  const int n4 = (4096 * 1024) / 4;
  int i = blockIdx.x * 256 + threadIdx.x;
  for (; i < n4; i += 2048 * 256) {
    float4 v = ((const float4*)x)[i];
    half4 h = { (_Float16)v.x, (_Float16)v.y, (_Float16)v.z, (_Float16)v.w };
    ((half4*)xh)[i] = h;
  }
}

// ------------- transpose+convert W (1024x1024) -> WT[n][k] fp16 -------------
__global__ void k_tw(const float* __restrict__ W0, const float* __restrict__ W1,
                     const float* __restrict__ W2, const float* __restrict__ W3,
                     _Float16* __restrict__ WT) {
  const float* W = (blockIdx.z == 0) ? W0 : (blockIdx.z == 1) ? W1 : (blockIdx.z == 2) ? W2 : W3;
  _Float16* out = WT + ((size_t)blockIdx.z << 20);
  __shared__ float t[32][33];
  const int x0 = blockIdx.x * 32;  // n
  const int y0 = blockIdx.y * 32;  // k
  const int tx = threadIdx.x, ty = threadIdx.y;  // (32,8)
#pragma unroll
  for (int r = 0; r < 4; ++r)
    t[ty + 8 * r][tx] = W[(size_t)(y0 + ty + 8 * r) * 1024 + x0 + tx];
  __syncthreads();
#pragma unroll
  for (int r = 0; r < 4; ++r)
    out[(size_t)(x0 + ty + 8 * r) * 1024 + y0 + tx] = (_Float16)t[tx][ty + 8 * r];
}

// ---------------- shared GEMM mainloop: C(128x128) = A(128xK) * B^T(128xK) ----------------
__device__ __forceinline__ void gemm_mainloop(const _Float16* __restrict__ A,
                                              const _Float16* __restrict__ Bmat,
                                              int m0, int n0,
                                              _Float16* As, _Float16* Bs,
                                              f32x4 acc[4][4]) {
  const int tid = threadIdx.x;
  const int lane = tid & 63;
  const int wid = tid >> 6;
  const int wm = wid >> 1, wn = wid & 1;
  const int c16 = lane & 15, rg = lane >> 4;

  for (int k0 = 0; k0 < 1024; k0 += 64) {
    __syncthreads();
#pragma unroll
    for (int i = 0; i < 4; ++i) {
      int e = (i * 256 + tid) * 8;       // element index within 128x64 tile
      int row = e >> 6;                  // 0..127
      int chunk = (e & 63) >> 3;         // 0..7 (16B chunk)
      int scol = ((chunk ^ (row & 7)) << 3);  // source-side swizzle (involution)
      gload_lds16(A + (size_t)(m0 + row) * 1024 + k0 + scol,
                  As + (size_t)(i * 256 + (wid << 6)) * 8);
      gload_lds16(Bmat + (size_t)(n0 + row) * 1024 + k0 + scol,
                  Bs + (size_t)(i * 256 + (wid << 6)) * 8);
    }
    __syncthreads();
#pragma unroll
    for (int kk = 0; kk < 2; ++kk) {
      half8 af[4], bfr[4];
#pragma unroll
      for (int mi = 0; mi < 4; ++mi) {
        int row = (wm << 6) + (mi << 4) + c16;
        int chunk = (kk << 2) + rg;
        af[mi] = *(const half8*)&As[(row << 6) + ((chunk ^ (row & 7)) << 3)];
      }
#pragma unroll
      for (int ni = 0; ni < 4; ++ni) {
        int row = (wn << 6) + (ni << 4) + c16;
        int chunk = (kk << 2) + rg;
        bfr[ni] = *(const half8*)&Bs[(row << 6) + ((chunk ^ (row & 7)) << 3)];
      }
#pragma unroll
      for (int mi = 0; mi < 4; ++mi)
#pragma unroll
        for (int ni = 0; ni < 4; ++ni)
          acc[mi][ni] = __builtin_amdgcn_mfma_f32_16x16x32_f16(af[mi], bfr[ni], acc[mi][ni], 0, 0, 0);
    }
  }
}

// ---------------- QKV GEMM + bias + RoPE + scatter ----------------
// Q -> [bh][t][d] scaled by (1/8)*log2(e) (exp2-domain softmax); K -> [bh][t][d];
// V -> transposed [bh][d][t]
__global__ __launch_bounds__(256, 2) void k_qkv(const _Float16* __restrict__ xh,
                                                const _Float16* __restrict__ WT,
                                                const float* __restrict__ bq,
                                                const float* __restrict__ bk,
                                                const float* __restrict__ bv,
                                                _Float16* __restrict__ Qh,
                                                _Float16* __restrict__ Kh,
                                                _Float16* __restrict__ VT) {
  __shared__ __align__(16) _Float16 As[128 * 64];
  __shared__ __align__(16) _Float16 Bs[128 * 64];
  f32x4 acc[4][4];
#pragma unroll
  for (int i = 0; i < 4; ++i)
#pragma unroll
    for (int j = 0; j < 4; ++j) acc[i][j] = (f32x4){0.f, 0.f, 0.f, 0.f};

  const int m0 = blockIdx.y * 128;
  const int ng = blockIdx.x * 128;   // 0..3071
  const int p = ng >> 10;            // 0=q,1=k,2=v
  const int n0 = ng & 1023;
  gemm_mainloop(xh, WT + ((size_t)p << 20), m0, n0, As, Bs, acc);

  const int tid = threadIdx.x, lane = tid & 63, wid = tid >> 6;
  const int wm = wid >> 1, wn = wid & 1, c16 = lane & 15, rg = lane >> 4;
  const float* bias = (p == 0) ? bq : (p == 1) ? bk : bv;
  const int nw = n0 + (wn << 6);
  const int head = nw >> 6;          // wave's 64-col strip is exactly one head
  float bi[4];
#pragma unroll
  for (int ni = 0; ni < 4; ++ni) bi[ni] = bias[nw + (ni << 4) + c16];

  if (p == 2) {  // V: store transposed [bh][d][t], vectorized half4 over t
#pragma unroll
    for (int mi = 0; mi < 4; ++mi) {
      int m = m0 + (wm << 6) + (mi << 4) + (rg << 2);
      int b = m >> 11, t0 = m & 2047;
#pragma unroll
      for (int ni = 0; ni < 4; ++ni) {
        half4 hv;
#pragma unroll
        for (int r = 0; r < 4; ++r) hv[r] = (_Float16)(acc[mi][ni][r] + bi[ni]);
        size_t base = ((size_t)(b * NH + head) * ND + (ni << 4) + c16) * NT + t0;
        *(half4*)&VT[base] = hv;
      }
    }
    return;
  }

  _Float16* Out = (p == 0) ? Qh : Kh;
  // inv_freq[c16] = 10000^(-c16/16) = 2^(-c16 * log2(10000)/16)  (accurate exp2)
  const float invf = exp2f((float)c16 * -0.8304820237218405f);
  // Q scale: (1/sqrt(64)) * log2(e)  -> S from MFMA is directly in exp2 domain
  const float qscale = (p == 0) ? 0.18033688011112042f : 1.0f;

#pragma unroll
  for (int mi = 0; mi < 4; ++mi) {
#pragma unroll
    for (int r = 0; r < 4; ++r) {
      int m = m0 + (wm << 6) + (mi << 4) + (rg << 2) + r;
      int b = m >> 11, t = m & 2047;
      float v0 = acc[mi][0][r] + bi[0];
      float v1 = acc[mi][1][r] + bi[1];
      float v2 = acc[mi][2][r] + bi[2];
      float v3 = acc[mi][3][r] + bi[3];
      {  // RoPE on d<32: pair (d, d+16)
        float th = (float)t * invf;
        float sn, cs;
        sincosf(th, &sn, &cs);   // theta reaches 2047 rad: needs libm range reduction
        float nx = v0 * cs - v1 * sn;
        v1 = v1 * cs + v0 * sn;
        v0 = nx;
      }
      size_t base = ((size_t)(b * NH + head) * NT + t) * ND;
      Out[base + 0 + c16]  = (_Float16)(v0 * qscale);
      Out[base + 16 + c16] = (_Float16)(v1 * qscale);
      Out[base + 32 + c16] = (_Float16)(v2 * qscale);
      Out[base + 48 + c16] = (_Float16)(v3 * qscale);
    }
  }
}

// ------- flash attention: 32-row q-tiles, in-block kv-split, 2 waves/block -------
// 2048 blocks x 128 thr; block = (bh, g): 32 q-rows [g*32, g*32+32). n = g+1 kv-iters
// split between the 2 waves ([0,nh2) / [nh2,n)); partials merged in-block via LDS.
// 16 waves/CU (4/SIMD). LPT: descending g at low blockIdx; bh = lin&31 -> 4 bh/XCD.
// Per-wave body: swapped QK^T 32x32, in-lane softmax, permlane P-repack, K-dbuf.
__global__ __launch_bounds__(128, 4) void k_attn(const _Float16* __restrict__ Qh,
                                                 const _Float16* __restrict__ Kh,
                                                 const _Float16* __restrict__ VT,
                                                 _Float16* __restrict__ Oh) {
  const int lin = blockIdx.x;            // 0..2047
  const int bh = lin & 31;               // XCD = lin%8 -> bh%8: 4 bh per XCD
  const int g = 63 - (lin >> 5);         // descending work (LPT)

  const int tid = threadIdx.x, lane = tid & 63, wid = tid >> 6;  // wid 0..1
  const int q31 = lane & 31, hi = lane >> 5;
  const size_t hb = (size_t)bh * NT * ND;
  const _Float16* Qp = Qh + hb;
  const _Float16* Kp = Kh + hb;
  const _Float16* Vp = VT + hb;
  const int b = bh >> 4, h = bh & 15;

  __shared__ float Osh[32][65];          // wave1 partial O (unnormalized), +1 pad
  __shared__ float msh[32], lsh[32];

  const int q0w = g << 5;                // the block's 32 q-rows
  const int qg = q0w + q31;
  const int n = g + 1;                   // total kv iterations (32 kv each)
  const int nh2 = (n + 1) >> 1;
  const int kt0   = (wid == 0) ? 0 : (nh2 << 5);
  const int ktend = (wid == 0) ? (nh2 << 5) : (n << 5);

  half8 qf[4];
#pragma unroll
  for (int c = 0; c < 4; ++c)
    qf[c] = *(const half8*)&Qp[(size_t)qg * ND + (c << 4) + (hi << 3)];

  f32x16 oacc0, oacc1;
#pragma unroll
  for (int r = 0; r < 16; ++r) { oacc0[r] = 0.f; oacc1[r] = 0.f; }
  float lacc[8];
#pragma unroll
  for (int r = 0; r < 8; ++r) lacc[r] = 0.f;
  float m = -INFINITY;

  half8 kA[4], kB[4], vfr[4];

#define LOADK(dst, ktv) do {                                                    \
    const _Float16* kp_ = Kp + (size_t)((ktv) + q31) * ND + (hi << 3);          \
    dst[0] = *(const half8*)(kp_);                                              \
    dst[1] = *(const half8*)(kp_ + 16);                                         \
    dst[2] = *(const half8*)(kp_ + 32);                                         \
    dst[3] = *(const half8*)(kp_ + 48);                                         \
  } while (0)

#define LOADV(ktv) do {                                                         \
    _Pragma("unroll")                                                           \
    for (int dh = 0; dh < 2; ++dh)                                              \
      _Pragma("unroll")                                                         \
      for (int ks = 0; ks < 2; ++ks)                                            \
        vfr[dh * 2 + ks] = *(const half8*)&Vp[(size_t)((dh << 5) + q31) * NT    \
                                              + (ktv) + (ks << 4) + (hi << 3)]; \
  } while (0)

#define BODY(kb, ktc) do {                                                      \
    f32x16 s;                                                                   \
    _Pragma("unroll")                                                           \
    for (int r = 0; r < 16; ++r) s[r] = 0.f;                                    \
    __builtin_amdgcn_s_setprio(1);                                              \
    _Pragma("unroll")                                                           \
    for (int c = 0; c < 4; ++c)                                                 \
      s = __builtin_amdgcn_mfma_f32_32x32x16_f16(kb[c], qf[c], s, 0, 0, 0);     \
    __builtin_amdgcn_s_setprio(0);                                              \
    if ((ktc) + 31 > q0w) {  /* causal mask: only the diagonal iteration */     \
      int rel = qg - (ktc) - (hi << 2);                                         \
      _Pragma("unroll")                                                         \
      for (int r = 0; r < 16; ++r) {                                            \
        int crow = (r & 3) + ((r >> 2) << 3);                                   \
        if (crow > rel) s[r] = -INFINITY;                                       \
      }                                                                         \
    }                                                                           \
    /* row max: depth-4 in-lane tree + cross-half shfl_xor */                   \
    float t8[8];                                                                \
    _Pragma("unroll")                                                           \
    for (int r = 0; r < 8; ++r) t8[r] = fmaxf(s[r], s[r + 8]);                  \
    _Pragma("unroll")                                                           \
    for (int r = 0; r < 4; ++r) t8[r] = fmaxf(t8[r], t8[r + 4]);                \
    float pm = fmaxf(fmaxf(t8[0], t8[1]), fmaxf(t8[2], t8[3]));                 \
    pm = fmaxf(pm, __shfl_xor(pm, 32));                                         \
    if (!__all(pm <= m + 11.54f)) {  /* defer-max, THR=8*log2e */               \
      float mn = fmaxf(m, pm);                                                  \
      float corr = exp2f(m - mn);                                               \
      m = mn;                                                                   \
      _Pragma("unroll")                                                         \
      for (int r = 0; r < 16; ++r) { oacc0[r] *= corr; oacc1[r] *= corr; }      \
      _Pragma("unroll")                                                         \
      for (int r = 0; r < 8; ++r) lacc[r] *= corr;                              \
    }                                                                           \
    _Pragma("unroll")                                                           \
    for (int r = 0; r < 16; ++r) {                                              \
      float pv = exp2f(s[r] - m);                                               \
      s[r] = pv;                                                                \
    }                                                                           \
    _Pragma("unroll")                                                           \
    for (int r = 0; r < 8; ++r) lacc[r] += s[r] + s[r + 8];                     \
    /* pack P to fp16; plswap(loWord, hiWord): r[0]->frag lo word, r[1]->hi */  \
    unsigned pw0 = __builtin_bit_cast(unsigned, __builtin_amdgcn_cvt_pkrtz(s[0], s[1]));   \
    unsigned pw1 = __builtin_bit_cast(unsigned, __builtin_amdgcn_cvt_pkrtz(s[2], s[3]));   \
    unsigned pw2 = __builtin_bit_cast(unsigned, __builtin_amdgcn_cvt_pkrtz(s[4], s[5]));   \
    unsigned pw3 = __builtin_bit_cast(unsigned, __builtin_amdgcn_cvt_pkrtz(s[6], s[7]));   \
    unsigned pw4 = __builtin_bit_cast(unsigned, __builtin_amdgcn_cvt_pkrtz(s[8], s[9]));   \
    unsigned pw5 = __builtin_bit_cast(unsigned, __builtin_amdgcn_cvt_pkrtz(s[10], s[11])); \
    unsigned pw6 = __builtin_bit_cast(unsigned, __builtin_amdgcn_cvt_pkrtz(s[12], s[13])); \
    unsigned pw7 = __builtin_bit_cast(unsigned, __builtin_amdgcn_cvt_pkrtz(s[14], s[15])); \
    uint2v rA0 = plswap(pw0, pw2);                                              \
    uint2v rA1 = plswap(pw1, pw3);                                              \
    uint2v rB0 = plswap(pw4, pw6);                                              \
    uint2v rB1 = plswap(pw5, pw7);                                              \
    uint4 ua, ub;                                                               \
    ua.x = rA0[0]; ua.y = rA1[0]; ua.z = rA0[1]; ua.w = rA1[1];                 \
    ub.x = rB0[0]; ub.y = rB1[0]; ub.z = rB0[1]; ub.w = rB1[1];                 \
    half8 pa0 = __builtin_bit_cast(half8, ua);                                  \
    half8 pa1 = __builtin_bit_cast(half8, ub);                                  \
    __builtin_amdgcn_s_setprio(1);                                              \
    oacc0 = __builtin_amdgcn_mfma_f32_32x32x16_f16(vfr[0], pa0, oacc0, 0, 0, 0); \
    oacc0 = __builtin_amdgcn_mfma_f32_32x32x16_f16(vfr[1], pa1, oacc0, 0, 0, 0); \
    oacc1 = __builtin_amdgcn_mfma_f32_32x32x16_f16(vfr[2], pa0, oacc1, 0, 0, 0); \
    oacc1 = __builtin_amdgcn_mfma_f32_32x32x16_f16(vfr[3], pa1, oacc1, 0, 0, 0); \
    __builtin_amdgcn_s_setprio(0);                                              \
  } while (0)

  // pipelined kv loop over this wave's range [kt0, ktend), KVBLK=32, K-dbuf
  int kt = kt0;
  if (kt < ktend) {
    LOADK(kA, kt);
    for (;;) {
      LOADV(kt);
      if (kt + 32 < ktend) LOADK(kB, kt + 32);
      __builtin_amdgcn_sched_barrier(0);
      BODY(kA, kt);
      kt += 32;
      if (kt >= ktend) break;
      LOADV(kt);
      if (kt + 32 < ktend) LOADK(kA, kt + 32);
      __builtin_amdgcn_sched_barrier(0);
      BODY(kB, kt);
      kt += 32;
      if (kt >= ktend) break;
    }
  }
#undef LOADK
#undef LOADV
#undef BODY

  // per-wave l reduction (in-lane tree + cross-half shfl)
  float l4[4];
#pragma unroll
  for (int r = 0; r < 4; ++r) l4[r] = lacc[r] + lacc[r + 4];
  float ls = (l4[0] + l4[1]) + (l4[2] + l4[3]);
  ls += __shfl_xor(ls, 32);

  // in-block combine: wave1 publishes partials, wave0 merges + stores
  if (wid == 1) {
    if (hi == 0) { msh[q31] = m; lsh[q31] = ls; }
#pragma unroll
    for (int g2 = 0; g2 < 4; ++g2)
#pragma unroll
      for (int r = 0; r < 4; ++r) {
        int d0 = (g2 << 3) + (hi << 2) + r;
        Osh[q31][d0] = oacc0[(g2 << 2) + r];
        Osh[q31][32 + d0] = oacc1[(g2 << 2) + r];
      }
  }
  __syncthreads();
  if (wid == 0) {
    float m1 = msh[q31], l1 = lsh[q31];
    float M = fmaxf(m, m1);
    float c0 = exp2f(m - M);
    float c1 = exp2f(m1 - M);      // empty wave1: m1=-inf -> c1=0
    float lt = c0 * ls + c1 * l1;
    float il = 1.f / lt;
    size_t obase = ((size_t)b * NT + qg) * NC + h * ND;
#pragma unroll
    for (int g2 = 0; g2 < 4; ++g2) {
      int d0 = (g2 << 3) + (hi << 2);
      half4 h4, h5;
#pragma unroll
      for (int r = 0; r < 4; ++r) {
        h4[r] = (_Float16)((c0 * oacc0[(g2 << 2) + r] + c1 * Osh[q31][d0 + r]) * il);
        h5[r] = (_Float16)((c0 * oacc1[(g2 << 2) + r] + c1 * Osh[q31][32 + d0 + r]) * il);
      }
      *(half4*)&Oh[obase + d0] = h4;
      *(half4*)&Oh[obase + 32 + d0] = h5;
    }
  }
}

// ---------------- output projection GEMM (fp32 out + bias) ----------------
__global__ __launch_bounds__(256, 2) void k_out(const _Float16* __restrict__ Oh,
                                                const _Float16* __restrict__ WoT,
                                                const float* __restrict__ bo,
                                                float* __restrict__ out) {
  __shared__ __align__(16) _Float16 As[128 * 64];
  __shared__ __align__(16) _Float16 Bs[128 * 64];
  f32x4 acc[4][4];
#pragma unroll
  for (int i = 0; i < 4; ++i)
#pragma unroll
    for (int j = 0; j < 4; ++j) acc[i][j] = (f32x4){0.f, 0.f, 0.f, 0.f};

  const int m0 = blockIdx.y * 128;
  const int n0 = blockIdx.x * 128;
  gemm_mainloop(Oh, WoT, m0, n0, As, Bs, acc);

  const int tid = threadIdx.x, lane = tid & 63, wid = tid >> 6;
  const int wm = wid >> 1, wn = wid & 1, c16 = lane & 15, rg = lane >> 4;
  float bi[4];
#pragma unroll
  for (int ni = 0; ni < 4; ++ni) bi[ni] = bo[n0 + (wn << 6) + (ni << 4) + c16];
#pragma unroll
  for (int mi = 0; mi < 4; ++mi) {
#pragma unroll
    for (int r = 0; r < 4; ++r) {
      int m = m0 + (wm << 6) + (mi << 4) + (rg << 2) + r;
#pragma unroll
      for (int ni = 0; ni < 4; ++ni) {
        int n = n0 + (wn << 6) + (ni << 4) + c16;
        out[(size_t)m * NC + n] = acc[mi][ni][r] + bi[ni];
      }
    }
  }
}

extern "C" void kernel_launch(void* const* d_in, const int* in_sizes, int n_in,
                              void* d_out, int out_size, void* d_ws, size_t ws_size,
                              hipStream_t stream) {
  const float* x  = (const float*)d_in[0];
  const float* Wq = (const float*)d_in[1];
  const float* bq = (const float*)d_in[2];
  const float* Wk = (const float*)d_in[3];
  const float* bk = (const float*)d_in[4];
  const float* Wv = (const float*)d_in[5];
  const float* bv = (const float*)d_in[6];
  const float* Wo = (const float*)d_in[7];
  const float* bo = (const float*)d_in[8];
  float* out = (float*)d_out;

  char* ws = (char*)d_ws;
  _Float16* xh = (_Float16*)ws;                       // 8 MB  [4096][1024]
  _Float16* WT = (_Float16*)(ws + (8ull << 20));      // 8 MB  [4][1024][1024] n-major
  _Float16* Qh = (_Float16*)(ws + (16ull << 20));     // 8 MB  [32][2048][64]
  _Float16* Kh = (_Float16*)(ws + (24ull << 20));     // 8 MB  [32][2048][64]
  _Float16* Vt = (_Float16*)(ws + (32ull << 20));     // 8 MB  [32][64][2048] (transposed)
  _Float16* Oh = (_Float16*)(ws + (40ull << 20));     // 8 MB  [4096][1024]

  k_cvt_x<<<2048, 256, 0, stream>>>(x, xh);
  k_tw<<<dim3(32, 32, 4), dim3(32, 8), 0, stream>>>(Wq, Wk, Wv, Wo, WT);
  k_qkv<<<dim3(24, 32), 256, 0, stream>>>(xh, WT, bq, bk, bv, Qh, Kh, Vt);
  k_attn<<<2048, 128, 0, stream>>>(Qh, Kh, Vt, Oh);
  k_out<<<dim3(8, 32), 256, 0, stream>>>(Oh, WT + (3ull << 20), bo, out);
}

// Round 13
// 133.205 us; speedup vs baseline: 1.8245x; 1.8245x over previous
//
#include <hip/hip_runtime.h>
#include <cstdint>
#include <cstddef>
#include <math.h>

typedef _Float16 half8 __attribute__((ext_vector_type(8)));
typedef _Float16 half4 __attribute__((ext_vector_type(4)));
typedef float f32x4 __attribute__((ext_vector_type(4)));
typedef float f32x16 __attribute__((ext_vector_type(16)));
typedef unsigned int uint2v __attribute__((ext_vector_type(2)));

#define NB  2
#define NT  2048
#define NC  1024
#define NH  16
#define ND  64

__device__ __forceinline__ void gload_lds16(const _Float16* g, _Float16* l) {
  __builtin_amdgcn_global_load_lds((const __attribute__((address_space(1))) void*)g,
                                   (__attribute__((address_space(3))) void*)l, 16, 0, 0);
}

// v_permlane32_swap_b32: r[0]={a.lo,b.lo}, r[1]={a.hi,b.hi}.
// NEVER call with a==b (same SSA value) — regalloc coalescing makes it a self-swap.
__device__ __forceinline__ uint2v plswap(unsigned a, unsigned b) {
  return __builtin_amdgcn_permlane32_swap(a, b, false, false);
}

// ---------------- convert x -> fp16 ----------------
__global__ void k_cvt_x(const float* __restrict__ x, _Float16* __restrict__ xh) {
  const int n4 = (4096 * 1024) / 4;
  int i = blockIdx.x * 256 + threadIdx.x;
  for (; i < n4; i += 2048 * 256) {
    float4 v = ((const float4*)x)[i];
    half4 h = { (_Float16)v.x, (_Float16)v.y, (_Float16)v.z, (_Float16)v.w };
    ((half4*)xh)[i] = h;
  }
}

// ------------- transpose+convert W (1024x1024) -> WT[n][k] fp16 -------------
__global__ void k_tw(const float* __restrict__ W0, const float* __restrict__ W1,
                     const float* __restrict__ W2, const float* __restrict__ W3,
                     _Float16* __restrict__ WT) {
  const float* W = (blockIdx.z == 0) ? W0 : (blockIdx.z == 1) ? W1 : (blockIdx.z == 2) ? W2 : W3;
  _Float16* out = WT + ((size_t)blockIdx.z << 20);
  __shared__ float t[32][33];
  const int x0 = blockIdx.x * 32;  // n
  const int y0 = blockIdx.y * 32;  // k
  const int tx = threadIdx.x, ty = threadIdx.y;  // (32,8)
#pragma unroll
  for (int r = 0; r < 4; ++r)
    t[ty + 8 * r][tx] = W[(size_t)(y0 + ty + 8 * r) * 1024 + x0 + tx];
  __syncthreads();
#pragma unroll
  for (int r = 0; r < 4; ++r)
    out[(size_t)(x0 + ty + 8 * r) * 1024 + y0 + tx] = (_Float16)t[tx][ty + 8 * r];
}

// ---------------- shared GEMM mainloop: C(128x128) = A(128xK) * B^T(128xK) ----------------
__device__ __forceinline__ void gemm_mainloop(const _Float16* __restrict__ A,
                                              const _Float16* __restrict__ Bmat,
                                              int m0, int n0,
                                              _Float16* As, _Float16* Bs,
                                              f32x4 acc[4][4]) {
  const int tid = threadIdx.x;
  const int lane = tid & 63;
  const int wid = tid >> 6;
  const int wm = wid >> 1, wn = wid & 1;
  const int c16 = lane & 15, rg = lane >> 4;

  for (int k0 = 0; k0 < 1024; k0 += 64) {
    __syncthreads();
#pragma unroll
    for (int i = 0; i < 4; ++i) {
      int e = (i * 256 + tid) * 8;       // element index within 128x64 tile
      int row = e >> 6;                  // 0..127
      int chunk = (e & 63) >> 3;         // 0..7 (16B chunk)
      int scol = ((chunk ^ (row & 7)) << 3);  // source-side swizzle (involution)
      gload_lds16(A + (size_t)(m0 + row) * 1024 + k0 + scol,
                  As + (size_t)(i * 256 + (wid << 6)) * 8);
      gload_lds16(Bmat + (size_t)(n0 + row) * 1024 + k0 + scol,
                  Bs + (size_t)(i * 256 + (wid << 6)) * 8);
    }
    __syncthreads();
#pragma unroll
    for (int kk = 0; kk < 2; ++kk) {
      half8 af[4], bfr[4];
#pragma unroll
      for (int mi = 0; mi < 4; ++mi) {
        int row = (wm << 6) + (mi << 4) + c16;
        int chunk = (kk << 2) + rg;
        af[mi] = *(const half8*)&As[(row << 6) + ((chunk ^ (row & 7)) << 3)];
      }
#pragma unroll
      for (int ni = 0; ni < 4; ++ni) {
        int row = (wn << 6) + (ni << 4) + c16;
        int chunk = (kk << 2) + rg;
        bfr[ni] = *(const half8*)&Bs[(row << 6) + ((chunk ^ (row & 7)) << 3)];
      }
#pragma unroll
      for (int mi = 0; mi < 4; ++mi)
#pragma unroll
        for (int ni = 0; ni < 4; ++ni)
          acc[mi][ni] = __builtin_amdgcn_mfma_f32_16x16x32_f16(af[mi], bfr[ni], acc[mi][ni], 0, 0, 0);
    }
  }
}

// ---------------- QKV GEMM + bias + RoPE + scatter ----------------
// Q -> [bh][t][d] scaled by (1/8)*log2(e) (exp2-domain softmax); K -> [bh][t][d];
// V -> transposed [bh][d][t]
__global__ __launch_bounds__(256, 2) void k_qkv(const _Float16* __restrict__ xh,
                                                const _Float16* __restrict__ WT,
                                                const float* __restrict__ bq,
                                                const float* __restrict__ bk,
                                                const float* __restrict__ bv,
                                                _Float16* __restrict__ Qh,
                                                _Float16* __restrict__ Kh,
                                                _Float16* __restrict__ VT) {
  __shared__ __align__(16) _Float16 As[128 * 64];
  __shared__ __align__(16) _Float16 Bs[128 * 64];
  f32x4 acc[4][4];
#pragma unroll
  for (int i = 0; i < 4; ++i)
#pragma unroll
    for (int j = 0; j < 4; ++j) acc[i][j] = (f32x4){0.f, 0.f, 0.f, 0.f};

  const int m0 = blockIdx.y * 128;
  const int ng = blockIdx.x * 128;   // 0..3071
  const int p = ng >> 10;            // 0=q,1=k,2=v
  const int n0 = ng & 1023;
  gemm_mainloop(xh, WT + ((size_t)p << 20), m0, n0, As, Bs, acc);

  const int tid = threadIdx.x, lane = tid & 63, wid = tid >> 6;
  const int wm = wid >> 1, wn = wid & 1, c16 = lane & 15, rg = lane >> 4;
  const float* bias = (p == 0) ? bq : (p == 1) ? bk : bv;
  const int nw = n0 + (wn << 6);
  const int head = nw >> 6;          // wave's 64-col strip is exactly one head
  float bi[4];
#pragma unroll
  for (int ni = 0; ni < 4; ++ni) bi[ni] = bias[nw + (ni << 4) + c16];

  if (p == 2) {  // V: store transposed [bh][d][t], vectorized half4 over t
#pragma unroll
    for (int mi = 0; mi < 4; ++mi) {
      int m = m0 + (wm << 6) + (mi << 4) + (rg << 2);
      int b = m >> 11, t0 = m & 2047;
#pragma unroll
      for (int ni = 0; ni < 4; ++ni) {
        half4 hv;
#pragma unroll
        for (int r = 0; r < 4; ++r) hv[r] = (_Float16)(acc[mi][ni][r] + bi[ni]);
        size_t base = ((size_t)(b * NH + head) * ND + (ni << 4) + c16) * NT + t0;
        *(half4*)&VT[base] = hv;
      }
    }
    return;
  }

  _Float16* Out = (p == 0) ? Qh : Kh;
  // inv_freq[c16] = 10000^(-c16/16) = 2^(-c16 * log2(10000)/16)  (accurate exp2)
  const float invf = exp2f((float)c16 * -0.8304820237218405f);
  // Q scale: (1/sqrt(64)) * log2(e)  -> S from MFMA is directly in exp2 domain
  const float qscale = (p == 0) ? 0.18033688011112042f : 1.0f;

#pragma unroll
  for (int mi = 0; mi < 4; ++mi) {
#pragma unroll
    for (int r = 0; r < 4; ++r) {
      int m = m0 + (wm << 6) + (mi << 4) + (rg << 2) + r;
      int b = m >> 11, t = m & 2047;
      float v0 = acc[mi][0][r] + bi[0];
      float v1 = acc[mi][1][r] + bi[1];
      float v2 = acc[mi][2][r] + bi[2];
      float v3 = acc[mi][3][r] + bi[3];
      {  // RoPE on d<32: pair (d, d+16)
        float th = (float)t * invf;
        float sn, cs;
        sincosf(th, &sn, &cs);   // theta reaches 2047 rad: needs libm range reduction
        float nx = v0 * cs - v1 * sn;
        v1 = v1 * cs + v0 * sn;
        v0 = nx;
      }
      size_t base = ((size_t)(b * NH + head) * NT + t) * ND;
      Out[base + 0 + c16]  = (_Float16)(v0 * qscale);
      Out[base + 16 + c16] = (_Float16)(v1 * qscale);
      Out[base + 32 + c16] = (_Float16)(v2 * qscale);
      Out[base + 48 + c16] = (_Float16)(v3 * qscale);
    }
  }
}

// ------ flash attention: 64-row tiles, 4 waves = 2 strips x (kv-lo, kv-hi) ------
// 1024 blocks x 256 thr; block = (bh, t): rows [t*64, t*64+64). Wave wid: strip
// s=wid&1 (32 rows), role=wid>>1 (0 = kv [0,nh2), 1 = kv [nh2,n)); n = 2t+s+1.
// Partials merged per strip via LDS. 16 waves/CU (4/SIMD). Const-sum co-residency:
// rounds get tiles {31-k, k, 23-k, 8+k} (sum 62) so each CU's 4 blocks equalize.
// Per-wave body: swapped QK^T 32x32, in-lane softmax, permlane P-repack, rotating
// K prefetch (single buffer, issued right after consumption).
__global__ __launch_bounds__(256, 4) void k_attn(const _Float16* __restrict__ Qh,
                                                 const _Float16* __restrict__ Kh,
                                                 const _Float16* __restrict__ VT,
                                                 _Float16* __restrict__ Oh) {
  const int lin = blockIdx.x;            // 0..1023
  const int xcd = lin & 7;
  const int slot = lin >> 3;             // 0..127 within XCD
  const int rnd = slot >> 5;             // co-residency round 0..3
  const int pos = slot & 31;
  const int bh = (xcd << 2) | (pos & 3); // 4 bh per XCD -> K+V 2MB in per-XCD L2
  const int k8 = pos >> 2;               // 0..7
  const int t = (rnd == 0) ? (31 - k8) : (rnd == 1) ? k8
              : (rnd == 2) ? (23 - k8) : (8 + k8);   // sums to 62 across rounds

  const int tid = threadIdx.x, lane = tid & 63, wid = tid >> 6;  // wid 0..3
  const int s_strip = wid & 1, role = wid >> 1;
  const int q31 = lane & 31, hi = lane >> 5;
  const size_t hb = (size_t)bh * NT * ND;
  const _Float16* Qp = Qh + hb;
  const _Float16* Kp = Kh + hb;
  const _Float16* Vp = VT + hb;
  const int b = bh >> 4, h = bh & 15;

  __shared__ float Osh[2][32][65];       // hi-role partial O per strip, +1 pad
  __shared__ float msh[2][32], lsh[2][32];

  const int q0w = (t << 6) + (s_strip << 5);  // this wave's 32 q-rows
  const int qg = q0w + q31;
  const int n = 2 * t + s_strip + 1;     // kv iterations (32 kv each) for this strip
  const int nh2 = (n + 1) >> 1;
  int it = role ? nh2 : 0;
  const int itend = role ? n : nh2;

  half8 qf[4];
#pragma unroll
  for (int c = 0; c < 4; ++c)
    qf[c] = *(const half8*)&Qp[(size_t)qg * ND + (c << 4) + (hi << 3)];

  f32x16 oacc0, oacc1;
#pragma unroll
  for (int r = 0; r < 16; ++r) { oacc0[r] = 0.f; oacc1[r] = 0.f; }
  float lacc[8];
#pragma unroll
  for (int r = 0; r < 8; ++r) lacc[r] = 0.f;
  float m = -INFINITY;

  half8 kA[4], vfr[4];

#define LOADK(ktv) do {                                                         \
    const _Float16* kp_ = Kp + (size_t)((ktv) + q31) * ND + (hi << 3);          \
    kA[0] = *(const half8*)(kp_);                                               \
    kA[1] = *(const half8*)(kp_ + 16);                                          \
    kA[2] = *(const half8*)(kp_ + 32);                                          \
    kA[3] = *(const half8*)(kp_ + 48);                                          \
  } while (0)

#define LOADV(ktv) do {                                                         \
    _Pragma("unroll")                                                           \
    for (int dh = 0; dh < 2; ++dh)                                              \
      _Pragma("unroll")                                                         \
      for (int ks = 0; ks < 2; ++ks)                                            \
        vfr[dh * 2 + ks] = *(const half8*)&Vp[(size_t)((dh << 5) + q31) * NT    \
                                              + (ktv) + (ks << 4) + (hi << 3)]; \
  } while (0)

  if (it < itend) {
    LOADK(it << 5);
    for (;;) {
      const int kt = it << 5;
      LOADV(kt);
      // ---- QK^T (swapped): s = S^T[kv][q] ----
      f32x16 s;
#pragma unroll
      for (int r = 0; r < 16; ++r) s[r] = 0.f;
      __builtin_amdgcn_s_setprio(1);
#pragma unroll
      for (int c = 0; c < 4; ++c)
        s = __builtin_amdgcn_mfma_f32_32x32x16_f16(kA[c], qf[c], s, 0, 0, 0);
      __builtin_amdgcn_s_setprio(0);
      // rotating K prefetch: kA consumed; refill for next iter, pinned early
      ++it;
      if (it < itend) {
        LOADK(it << 5);
        __builtin_amdgcn_sched_barrier(0);
      }
      // ---- causal mask: only the strip's final iteration ----
      if (kt + 31 > q0w) {
        int rel = qg - kt - (hi << 2);
#pragma unroll
        for (int r = 0; r < 16; ++r) {
          int crow = (r & 3) + ((r >> 2) << 3);
          if (crow > rel) s[r] = -INFINITY;
        }
      }
      // ---- row max: in-lane tree + cross-half shfl ----
      float t8[8];
#pragma unroll
      for (int r = 0; r < 8; ++r) t8[r] = fmaxf(s[r], s[r + 8]);
#pragma unroll
      for (int r = 0; r < 4; ++r) t8[r] = fmaxf(t8[r], t8[r + 4]);
      float pm = fmaxf(fmaxf(t8[0], t8[1]), fmaxf(t8[2], t8[3]));
      pm = fmaxf(pm, __shfl_xor(pm, 32));
      if (!__all(pm <= m + 11.54f)) {  // defer-max, THR=8*log2e
        float mn = fmaxf(m, pm);
        float corr = exp2f(m - mn);
        m = mn;
#pragma unroll
        for (int r = 0; r < 16; ++r) { oacc0[r] *= corr; oacc1[r] *= corr; }
#pragma unroll
        for (int r = 0; r < 8; ++r) lacc[r] *= corr;
      }
#pragma unroll
      for (int r = 0; r < 16; ++r) s[r] = exp2f(s[r] - m);
#pragma unroll
      for (int r = 0; r < 8; ++r) lacc[r] += s[r] + s[r + 8];
      // ---- pack P; plswap(loWord, hiWord): r[0]->frag lo word, r[1]->hi ----
      unsigned pw0 = __builtin_bit_cast(unsigned, __builtin_amdgcn_cvt_pkrtz(s[0], s[1]));
      unsigned pw1 = __builtin_bit_cast(unsigned, __builtin_amdgcn_cvt_pkrtz(s[2], s[3]));
      unsigned pw2 = __builtin_bit_cast(unsigned, __builtin_amdgcn_cvt_pkrtz(s[4], s[5]));
      unsigned pw3 = __builtin_bit_cast(unsigned, __builtin_amdgcn_cvt_pkrtz(s[6], s[7]));
      unsigned pw4 = __builtin_bit_cast(unsigned, __builtin_amdgcn_cvt_pkrtz(s[8], s[9]));
      unsigned pw5 = __builtin_bit_cast(unsigned, __builtin_amdgcn_cvt_pkrtz(s[10], s[11]));
      unsigned pw6 = __builtin_bit_cast(unsigned, __builtin_amdgcn_cvt_pkrtz(s[12], s[13]));
      unsigned pw7 = __builtin_bit_cast(unsigned, __builtin_amdgcn_cvt_pkrtz(s[14], s[15]));
      uint2v rA0 = plswap(pw0, pw2);
      uint2v rA1 = plswap(pw1, pw3);
      uint2v rB0 = plswap(pw4, pw6);
      uint2v rB1 = plswap(pw5, pw7);
      uint4 ua, ub;
      ua.x = rA0[0]; ua.y = rA1[0]; ua.z = rA0[1]; ua.w = rA1[1];
      ub.x = rB0[0]; ub.y = rB1[0]; ub.z = rB0[1]; ub.w = rB1[1];
      half8 pa0 = __builtin_bit_cast(half8, ua);
      half8 pa1 = __builtin_bit_cast(half8, ub);
      __builtin_amdgcn_s_setprio(1);
      oacc0 = __builtin_amdgcn_mfma_f32_32x32x16_f16(vfr[0], pa0, oacc0, 0, 0, 0);
      oacc0 = __builtin_amdgcn_mfma_f32_32x32x16_f16(vfr[1], pa1, oacc0, 0, 0, 0);
      oacc1 = __builtin_amdgcn_mfma_f32_32x32x16_f16(vfr[2], pa0, oacc1, 0, 0, 0);
      oacc1 = __builtin_amdgcn_mfma_f32_32x32x16_f16(vfr[3], pa1, oacc1, 0, 0, 0);
      __builtin_amdgcn_s_setprio(0);
      if (it >= itend) break;
    }
  }
#undef LOADK
#undef LOADV

  // per-wave l reduction (in-lane tree + cross-half shfl)
  float l4[4];
#pragma unroll
  for (int r = 0; r < 4; ++r) l4[r] = lacc[r] + lacc[r + 4];
  float ls = (l4[0] + l4[1]) + (l4[2] + l4[3]);
  ls += __shfl_xor(ls, 32);

  // merge: hi-role waves publish partials, lo-role waves combine + store
  if (role == 1) {
    if (hi == 0) { msh[s_strip][q31] = m; lsh[s_strip][q31] = ls; }
#pragma unroll
    for (int g2 = 0; g2 < 4; ++g2)
#pragma unroll
      for (int r = 0; r < 4; ++r) {
        int d0 = (g2 << 3) + (hi << 2) + r;
        Osh[s_strip][q31][d0] = oacc0[(g2 << 2) + r];
        Osh[s_strip][q31][32 + d0] = oacc1[(g2 << 2) + r];
      }
  }
  __syncthreads();
  if (role == 0) {
    float m1 = msh[s_strip][q31], l1 = lsh[s_strip][q31];
    float M = fmaxf(m, m1);
    float c0 = exp2f(m - M);
    float c1 = exp2f(m1 - M);      // empty hi-half: m1=-inf -> c1=0
    float lt = c0 * ls + c1 * l1;
    float il = 1.f / lt;
    size_t obase = ((size_t)b * NT + qg) * NC + h * ND;
#pragma unroll
    for (int g2 = 0; g2 < 4; ++g2) {
      int d0 = (g2 << 3) + (hi << 2);
      half4 h4, h5;
#pragma unroll
      for (int r = 0; r < 4; ++r) {
        h4[r] = (_Float16)((c0 * oacc0[(g2 << 2) + r] + c1 * Osh[s_strip][q31][d0 + r]) * il);
        h5[r] = (_Float16)((c0 * oacc1[(g2 << 2) + r] + c1 * Osh[s_strip][q31][32 + d0 + r]) * il);
      }
      *(half4*)&Oh[obase + d0] = h4;
      *(half4*)&Oh[obase + 32 + d0] = h5;
    }
  }
}

// ---------------- output projection GEMM (fp32 out + bias) ----------------
__global__ __launch_bounds__(256, 2) void k_out(const _Float16* __restrict__ Oh,
                                                const _Float16* __restrict__ WoT,
                                                const float* __restrict__ bo,
                                                float* __restrict__ out) {
  __shared__ __align__(16) _Float16 As[128 * 64];
  __shared__ __align__(16) _Float16 Bs[128 * 64];
  f32x4 acc[4][4];
#pragma unroll
  for (int i = 0; i < 4; ++i)
#pragma unroll
    for (int j = 0; j < 4; ++j) acc[i][j] = (f32x4){0.f, 0.f, 0.f, 0.f};

  const int m0 = blockIdx.y * 128;
  const int n0 = blockIdx.x * 128;
  gemm_mainloop(Oh, WoT, m0, n0, As, Bs, acc);

  const int tid = threadIdx.x, lane = tid & 63, wid = tid >> 6;
  const int wm = wid >> 1, wn = wid & 1, c16 = lane & 15, rg = lane >> 4;
  float bi[4];
#pragma unroll
  for (int ni = 0; ni < 4; ++ni) bi[ni] = bo[n0 + (wn << 6) + (ni << 4) + c16];
#pragma unroll
  for (int mi = 0; mi < 4; ++mi) {
#pragma unroll
    for (int r = 0; r < 4; ++r) {
      int m = m0 + (wm << 6) + (mi << 4) + (rg << 2) + r;
#pragma unroll
      for (int ni = 0; ni < 4; ++ni) {
        int n = n0 + (wn << 6) + (ni << 4) + c16;
        out[(size_t)m * NC + n] = acc[mi][ni][r] + bi[ni];
      }
    }
  }
}

extern "C" void kernel_launch(void* const* d_in, const int* in_sizes, int n_in,
                              void* d_out, int out_size, void* d_ws, size_t ws_size,
                              hipStream_t stream) {
  const float* x  = (const float*)d_in[0];
  const float* Wq = (const float*)d_in[1];
  const float* bq = (const float*)d_in[2];
  const float* Wk = (const float*)d_in[3];
  const float* bk = (const float*)d_in[4];
  const float* Wv = (const float*)d_in[5];
  const float* bv = (const float*)d_in[6];
  const float* Wo = (const float*)d_in[7];
  const float* bo = (const float*)d_in[8];
  float* out = (float*)d_out;

  char* ws = (char*)d_ws;
  _Float16* xh = (_Float16*)ws;                       // 8 MB  [4096][1024]
  _Float16* WT = (_Float16*)(ws + (8ull << 20));      // 8 MB  [4][1024][1024] n-major
  _Float16* Qh = (_Float16*)(ws + (16ull << 20));     // 8 MB  [32][2048][64]
  _Float16* Kh = (_Float16*)(ws + (24ull << 20));     // 8 MB  [32][2048][64]
  _Float16* Vt = (_Float16*)(ws + (32ull << 20));     // 8 MB  [32][64][2048] (transposed)
  _Float16* Oh = (_Float16*)(ws + (40ull << 20));     // 8 MB  [4096][1024]

  k_cvt_x<<<2048, 256, 0, stream>>>(x, xh);
  k_tw<<<dim3(32, 32, 4), dim3(32, 8), 0, stream>>>(Wq, Wk, Wv, Wo, WT);
  k_qkv<<<dim3(24, 32), 256, 0, stream>>>(xh, WT, bq, bk, bv, Qh, Kh, Vt);
  k_attn<<<1024, 256, 0, stream>>>(Qh, Kh, Vt, Oh);
  k_out<<<dim3(8, 32), 256, 0, stream>>>(Oh, WT + (3ull << 20), bo, out);
}